// Round 6
// baseline (539.722 us; speedup 1.0000x reference)
//
#include <hip/hip_runtime.h>

// Problem constants
#define BB 16
#define SS 8192
#define DD 512   // Q_DIM == K_DIM == ATTN_DIM

typedef float  f32x4  __attribute__((ext_vector_type(4)));
typedef __bf16 bf16x8 __attribute__((ext_vector_type(8)));
typedef __bf16 bf16x4 __attribute__((ext_vector_type(4)));

__device__ __forceinline__ void cvt_store_bf4(unsigned short* dst, f32x4 v) {
    bf16x4 o;
    o.x = (__bf16)v.x; o.y = (__bf16)v.y; o.z = (__bf16)v.z; o.w = (__bf16)v.w;
    *(bf16x4*)dst = o;   // 8-byte LDS store
}

__device__ __forceinline__ float tanh_fast(float x) {
    float e2 = __expf(2.0f * x);
    return 1.0f - 2.0f / (e2 + 1.0f);   // -> +/-1 correctly as e2 -> inf/0
}

// ---------------------------------------------------------------------------
// Kernel 1: blocks 0..63: WkT_f = bf16(Wk^T) in MFMA-fragment order:
//   element (n,k) -> WkT_f[ ((g*16 + j)*64 + lane)*8 + d ]
//   g=n>>4, ml=n&15, j=k>>5, quad=(k>>3)&3, d=k&7, lane=quad*16+ml
// blocks 64..95: qproj = query @ Wq (fp32), one output per thread
// ---------------------------------------------------------------------------
__global__ __launch_bounds__(256) void prep_kernel(
    const float* __restrict__ query, const float* __restrict__ Wq,
    const float* __restrict__ Wk, float* __restrict__ qproj,
    unsigned short* __restrict__ WkT_f)
{
    __shared__ __bf16 lt[64][65];
    const int bid = blockIdx.x, t = threadIdx.x;
    if (bid < 64) {                        // 8x8 grid of 64x64 (k,n) tiles
        const int k0 = (bid >> 3) * 64, n0 = (bid & 7) * 64;
#pragma unroll
        for (int rep = 0; rep < 4; ++rep) {       // coalesced read
            const int k = rep * 16 + (t >> 4), n = (t & 15) * 4;
            f32x4 vv = *(const f32x4*)&Wk[(size_t)(k0 + k) * DD + n0 + n];
            lt[k][n] = (__bf16)vv.x; lt[k][n + 1] = (__bf16)vv.y;
            lt[k][n + 2] = (__bf16)vv.z; lt[k][n + 3] = (__bf16)vv.w;
        }
        __syncthreads();
        const int g_loc = t >> 6, lane = t & 63;
        const int ml = lane & 15, quad = lane >> 4;
        const int g = (bid & 7) * 4 + g_loc;
#pragma unroll
        for (int j_loc = 0; j_loc < 2; ++j_loc) {
            const int j = (bid >> 3) * 2 + j_loc;
            bf16x8 o;
#pragma unroll
            for (int d = 0; d < 8; ++d)
                o[d] = lt[j_loc * 32 + quad * 8 + d][g_loc * 16 + ml];
            *(bf16x8*)&WkT_f[((size_t)((g * 16 + j) * 64 + lane)) * 8] = o;
        }
    } else {                               // qproj: 8192 outputs, one per thread
        const int idx = (bid - 64) * 256 + t;
        const int b = idx >> 9;
        const int n = idx & 511;
        const float* q  = query + b * DD;
        const float* wp = Wq + n;
        float acc = 0.0f;
#pragma unroll 8
        for (int k = 0; k < DD; ++k)
            acc = fmaf(q[k], wp[(size_t)k * DD], acc);
        qproj[b * DD + n] = acc;
    }
}

// ---------------------------------------------------------------------------
// Kernel 2 (fused, persistent): 256 blocks (1/CU), 1024 threads / 16 waves.
// Each block: one batch row b, 8 consecutive 64-row s-chunks.
// Per chunk: prefetch next chunk's keys into regs BEFORE the K-loop (HBM
// latency hidden behind MFMA), double-buffered LDS A-tile, B from L2-resident
// WkT_f (contiguous 1KB per wave-load). Then stats + context while L2-hot.
// Wave w owns n-slice [32w, 32w+32) -> acc 4x2 (32 VGPR).
// ---------------------------------------------------------------------------
__global__ __launch_bounds__(1024, 4) void fused_kernel(
    const float* __restrict__ keys, const unsigned short* __restrict__ WkT_f,
    const float* __restrict__ qproj, const float* __restrict__ vvec,
    const int* __restrict__ mask, float* __restrict__ e_ws,
    float* __restrict__ cpart, float2* __restrict__ ml_ws)
{
    __shared__ unsigned short ksA[2][16 * 2048];  // 2 x 64 KB, fragment-major
    __shared__ float sm_part[16][64];             // 4 KB
    __shared__ float w_sh[64];
    __shared__ f32x4 red[7][128];                 // 14 KB

    const int tid  = threadIdx.x;
    const int w    = tid >> 6;        // wave 0..15 -> n slice [32w, 32w+32)
    const int lane = tid & 63;
    const int ml   = lane & 15;
    const int quad = lane >> 4;
    const int bid  = blockIdx.x;
    const int b    = bid >> 4;        // 16 blocks per batch row
    const int grp  = bid & 15;        // s-range [grp*512, grp*512+512)
    const int sgrp = grp << 9;

    // --- staging map: thread t covers row m = t>>4, f32x4 #(q16 + 16h) ---
    const int m   = tid >> 4;
    const int q16 = tid & 15;
    const int it  = m >> 4;
    const int base = it * 512 + ((m & 15) + 16 * ((q16 & 7) >> 1)) * 8 + (q16 & 1) * 4;
    const int jb  = q16 >> 3;         // store j = jb + 2h
    const float* kr = keys + ((size_t)(b * SS + sgrp + m)) * DD + q16 * 4;

    // --- B pointer: wave-contiguous fragments ---
    const unsigned short* wfb = WkT_f + (size_t)w * 16384 + lane * 8;

    // --- per-wave epilogue constants ---
    float qv[2], vv[2];
#pragma unroll
    for (int jn = 0; jn < 2; ++jn) {
        const int n = w * 32 + jn * 16 + ml;
        qv[jn] = qproj[b * DD + n];
        vv[jn] = vvec[n];
    }

    // --- prologue: stage chunk 0 into buffer 0 ---
    {
        f32x4 tmp[8];
#pragma unroll
        for (int h = 0; h < 8; ++h) tmp[h] = *(const f32x4*)(kr + h * 64);
#pragma unroll
        for (int h = 0; h < 8; ++h) cvt_store_bf4(&ksA[0][(jb + 2 * h) * 2048 + base], tmp[h]);
    }
    __syncthreads();

    for (int i = 0; i < 8; ++i) {
        const int cur = i & 1, nxt = cur ^ 1;
        const int scur = sgrp + i * 64;

        // prefetch chunk i+1 into registers (in flight during K-loop)
        f32x4 tmp[8];
        if (i < 7) {
            const float* krn = kr + (size_t)(i + 1) * 64 * DD;
#pragma unroll
            for (int h = 0; h < 8; ++h) tmp[h] = *(const f32x4*)(krn + h * 64);
        }

        // --- K-loop: A from LDS buf cur, B from L2 ---
        f32x4 acc[4][2];
#pragma unroll
        for (int ii = 0; ii < 4; ++ii)
#pragma unroll
            for (int jn = 0; jn < 2; ++jn) acc[ii][jn] = (f32x4){0.f, 0.f, 0.f, 0.f};

#pragma unroll 4
        for (int j = 0; j < 16; ++j) {
            bf16x8 af[4];
#pragma unroll
            for (int ii = 0; ii < 4; ++ii)
                af[ii] = *(const bf16x8*)&ksA[cur][j * 2048 + (ii * 64 + lane) * 8];
#pragma unroll
            for (int jn = 0; jn < 2; ++jn) {
                bf16x8 bfr = *(const bf16x8*)(wfb + ((jn * 16 + j) << 9));
#pragma unroll
                for (int ii = 0; ii < 4; ++ii)
                    acc[ii][jn] = __builtin_amdgcn_mfma_f32_16x16x32_bf16(af[ii], bfr, acc[ii][jn], 0, 0, 0);
            }
        }

        // store prefetched chunk into the idle buffer (loads completed during K-loop)
        if (i < 7) {
#pragma unroll
            for (int h = 0; h < 8; ++h)
                cvt_store_bf4(&ksA[nxt][(jb + 2 * h) * 2048 + base], tmp[h]);
        }

        // --- epilogue: e-partials. C layout: row = quad*4 + reg, col = ml ---
#pragma unroll
        for (int ii = 0; ii < 4; ++ii) {
#pragma unroll
            for (int r = 0; r < 4; ++r) {
                float s = 0.0f;
#pragma unroll
                for (int jn = 0; jn < 2; ++jn) {
                    float xx = acc[ii][jn][r] + qv[jn];
                    s += tanh_fast(xx) * vv[jn];
                }
                s += __shfl_xor(s, 1, 64);
                s += __shfl_xor(s, 2, 64);
                s += __shfl_xor(s, 4, 64);
                s += __shfl_xor(s, 8, 64);
                if (ml == 0) sm_part[w][ii * 16 + quad * 4 + r] = s;
            }
        }
        __syncthreads();

        // --- block-local softmax stats (wave 0) ---
        if (tid < 64) {
            float e = 0.0f;
#pragma unroll
            for (int wv = 0; wv < 16; ++wv) e += sm_part[wv][tid];
            const int mk = mask[b * SS + scur + tid];
            if (mk == 0) e = -3.402823466e38f;
            e_ws[(size_t)b * SS + scur + tid] = e;
            float mx = e;
#pragma unroll
            for (int off = 32; off >= 1; off >>= 1) mx = fmaxf(mx, __shfl_xor(mx, off, 64));
            float wgt = (mk == 0) ? 0.0f : __expf(e - mx);
            float l = wgt;
#pragma unroll
            for (int off = 32; off >= 1; off >>= 1) l += __shfl_xor(l, off, 64);
            w_sh[tid] = wgt;
            if (tid == 0) ml_ws[b * 128 + grp * 8 + i] = make_float2(mx, l);
        }
        __syncthreads();

        // --- context partial: 8 s-groups x 128 n-threads, keys L2-hot ---
        const int n4 = (tid & 127) << 2;
        const int sh = tid >> 7;                  // 0..7, 8 s-rows each
        const float* kctx = keys + ((size_t)(b * SS + scur + sh * 8)) * DD + n4;
        f32x4 cacc = (f32x4){0.f, 0.f, 0.f, 0.f};
#pragma unroll
        for (int sI = 0; sI < 8; ++sI) {
            float wgt = w_sh[sh * 8 + sI];
            f32x4 kv  = *(const f32x4*)(kctx + (size_t)sI * DD);
            cacc += kv * wgt;
        }
        if (sh) red[sh - 1][tid & 127] = cacc;
        __syncthreads();
        if (sh == 0) {
#pragma unroll
            for (int g2 = 0; g2 < 7; ++g2) cacc += red[g2][tid];
            *(f32x4*)(cpart + ((size_t)(b * 128 + grp * 8 + i)) * 512 + n4) = cacc;
        }
    }
}

// ---------------------------------------------------------------------------
// Kernel 3: finalize.
//  blocks 0..15:    c[b][n] = (sum_i cpart[b][i][n]*exp(m_i-M)) / L
//  blocks 16..143:  a[b][s] = exp(e[b][s]-M)/L   (1024 s per block)
// ---------------------------------------------------------------------------
__global__ __launch_bounds__(256) void finalize_kernel(
    const float* __restrict__ e_ws, const float* __restrict__ cpart,
    const float2* __restrict__ ml_ws, float* __restrict__ out)
{
    __shared__ float rm[4], rs[4];
    __shared__ float sc_sh[128];
    __shared__ float cred[4][512];
    const int bid = blockIdx.x, t = threadIdx.x;
    const int b = (bid < 16) ? bid : ((bid - 16) >> 3);

    float mi = -3.402823466e38f, li = 0.0f;
    if (t < 128) { float2 p = ml_ws[b * 128 + t]; mi = p.x; li = p.y; }
    float mr = mi;
#pragma unroll
    for (int off = 32; off >= 1; off >>= 1) mr = fmaxf(mr, __shfl_xor(mr, off, 64));
    if ((t & 63) == 0) rm[t >> 6] = mr;
    __syncthreads();
    const float M = fmaxf(fmaxf(rm[0], rm[1]), fmaxf(rm[2], rm[3]));
    float si = (t < 128) ? li * __expf(mi - M) : 0.0f;
#pragma unroll
    for (int off = 32; off >= 1; off >>= 1) si += __shfl_xor(si, off, 64);
    if ((t & 63) == 0) rs[t >> 6] = si;
    __syncthreads();
    const float L = rs[0] + rs[1] + rs[2] + rs[3];
    const float invL = 1.0f / L;

    if (bid < 16) {
        if (t < 128) sc_sh[t] = __expf(ml_ws[b * 128 + t].x - M);
        __syncthreads();
        const int w2 = t >> 6, l = t & 63;
        float pa[8] = {0.f, 0.f, 0.f, 0.f, 0.f, 0.f, 0.f, 0.f};
#pragma unroll 4
        for (int i = w2 * 32; i < w2 * 32 + 32; ++i) {
            const float sc = sc_sh[i];
            const float* cp = cpart + ((size_t)(b * 128 + i)) * 512 + l * 8;
#pragma unroll
            for (int c = 0; c < 8; ++c) pa[c] = fmaf(cp[c], sc, pa[c]);
        }
#pragma unroll
        for (int c = 0; c < 8; ++c) cred[w2][l * 8 + c] = pa[c];
        __syncthreads();
#pragma unroll
        for (int rep = 0; rep < 2; ++rep) {
            const int n = t + rep * 256;
            out[b * DD + n] = (cred[0][n] + cred[1][n] + cred[2][n] + cred[3][n]) * invL;
        }
    } else {
        const int chunk8 = (bid - 16) & 7;
        const float* ep = e_ws + (size_t)b * SS + chunk8 * 1024;
        float* ap = out + BB * DD + (size_t)b * SS + chunk8 * 1024;
#pragma unroll
        for (int r = 0; r < 4; ++r) {
            float e = ep[t + 256 * r];
            ap[t + 256 * r] = __expf(e - M) * invL;
        }
    }
}

// ---------------------------------------------------------------------------
extern "C" void kernel_launch(void* const* d_in, const int* in_sizes, int n_in,
                              void* d_out, int out_size, void* d_ws, size_t ws_size,
                              hipStream_t stream)
{
    const float* query = (const float*)d_in[0];
    const float* keys  = (const float*)d_in[1];
    const int*   mask  = (const int*)  d_in[2];
    const float* Wq    = (const float*)d_in[3];
    const float* Wk    = (const float*)d_in[4];
    const float* v     = (const float*)d_in[5];
    float* out = (float*)d_out;

    float*          qproj = (float*)d_ws;                                     // 32 KB
    unsigned short* WkT_f = (unsigned short*)((char*)d_ws + 32768);           // 512 KB
    float*          e_ws  = (float*)((char*)d_ws + 32768 + 524288);           // 512 KB
    float*          cpart = (float*)((char*)d_ws + 32768 + 2 * 524288);       // 4 MB
    float2*         ml_ws = (float2*)((char*)d_ws + 32768 + 2 * 524288 + 4194304); // 16 KB

    prep_kernel    <<<96, 256, 0, stream>>>(query, Wq, Wk, qproj, WkT_f);
    fused_kernel   <<<256, 1024, 0, stream>>>(keys, WkT_f, qproj, v, mask,
                                              e_ws, cpart, ml_ws);
    finalize_kernel<<<16 + 128, 256, 0, stream>>>(e_ws, cpart, ml_ws, out);
}

// Round 7
// 538.030 us; speedup vs baseline: 1.0031x; 1.0031x over previous
//
#include <hip/hip_runtime.h>

// Problem constants
#define BB 16
#define SS 8192
#define DD 512   // Q_DIM == K_DIM == ATTN_DIM

typedef float  f32x4  __attribute__((ext_vector_type(4)));
typedef __bf16 bf16x8 __attribute__((ext_vector_type(8)));
typedef __bf16 bf16x4 __attribute__((ext_vector_type(4)));

#define NEG_HUGE -3.402823466e38f

__device__ __forceinline__ void cvt_store_bf4(unsigned short* dst, f32x4 v) {
    bf16x4 o;
    o.x = (__bf16)v.x; o.y = (__bf16)v.y; o.z = (__bf16)v.z; o.w = (__bf16)v.w;
    *(bf16x4*)dst = o;   // 8-byte LDS store
}

// ---------------------------------------------------------------------------
// Kernel 1: blocks 0..63: WkT_f = bf16(Wk^T) in MFMA-fragment order:
//   element (n,k) -> WkT_f[ ((g*16 + j)*64 + lane)*8 + d ]
//   g=n>>4, ml=n&15, j=k>>5, quad=(k>>3)&3, d=k&7, lane=quad*16+ml
// blocks 64..95: qproj = query @ Wq (fp32), one output per thread
// ---------------------------------------------------------------------------
__global__ __launch_bounds__(256) void prep_kernel(
    const float* __restrict__ query, const float* __restrict__ Wq,
    const float* __restrict__ Wk, float* __restrict__ qproj,
    unsigned short* __restrict__ WkT_f)
{
    __shared__ __bf16 lt[64][65];
    const int bid = blockIdx.x, t = threadIdx.x;
    if (bid < 64) {                        // 8x8 grid of 64x64 (k,n) tiles
        const int k0 = (bid >> 3) * 64, n0 = (bid & 7) * 64;
#pragma unroll
        for (int rep = 0; rep < 4; ++rep) {       // coalesced read
            const int k = rep * 16 + (t >> 4), n = (t & 15) * 4;
            f32x4 vv = *(const f32x4*)&Wk[(size_t)(k0 + k) * DD + n0 + n];
            lt[k][n] = (__bf16)vv.x; lt[k][n + 1] = (__bf16)vv.y;
            lt[k][n + 2] = (__bf16)vv.z; lt[k][n + 3] = (__bf16)vv.w;
        }
        __syncthreads();
        const int g_loc = t >> 6, lane = t & 63;
        const int ml = lane & 15, quad = lane >> 4;
        const int g = (bid & 7) * 4 + g_loc;
#pragma unroll
        for (int j_loc = 0; j_loc < 2; ++j_loc) {
            const int j = (bid >> 3) * 2 + j_loc;
            bf16x8 o;
#pragma unroll
            for (int d = 0; d < 8; ++d)
                o[d] = lt[j_loc * 32 + quad * 8 + d][g_loc * 16 + ml];
            *(bf16x8*)&WkT_f[((size_t)((g * 16 + j) * 64 + lane)) * 8] = o;
        }
    } else {                               // qproj: 8192 outputs, one per thread
        const int idx = (bid - 64) * 256 + t;
        const int b = idx >> 9;
        const int n = idx & 511;
        const float* q  = query + b * DD;
        const float* wp = Wq + n;
        float acc = 0.0f;
#pragma unroll 8
        for (int k = 0; k < DD; ++k)
            acc = fmaf(q[k], wp[(size_t)k * DD], acc);
        qproj[b * DD + n] = acc;
    }
}

// ---------------------------------------------------------------------------
// Kernel 2 (fused, persistent, software-pipelined):
// 512 blocks (exactly 2/CU), 512 threads / 8 waves. Block owns 256 s-rows of
// one batch row = 8 chunks x 32 rows. Per chunk: issue next chunk's keys
// loads (pinned above K-loop by sched_barrier), K-loop on current 32KB LDS
// A-buffer (B straight from L2-resident WkT_f), cvt+store prefetch into idle
// buffer, epilogue tanh-dot, 32-thread stats with block-level ONLINE softmax
// (c_run rescale), column-per-thread context from L2-hot keys.
// Two barriers per chunk; they double as LDS ping-pong hazard guards.
// ---------------------------------------------------------------------------
__global__ __launch_bounds__(512, 4) void fused_kernel(
    const float* __restrict__ keys, const unsigned short* __restrict__ WkT_f,
    const float* __restrict__ qproj, const float* __restrict__ vvec,
    const int* __restrict__ mask, float* __restrict__ e_ws,
    float* __restrict__ cpart, float2* __restrict__ ml_ws)
{
    __shared__ unsigned short ksA[2][16 * 1024];  // 2 x 32 KB, [j][it][lane'][8]
    __shared__ float sm_part[8][32];
    __shared__ float w_sh[32];
    __shared__ float c_run[512];
    __shared__ int   mask_sh[256];
    __shared__ float mrun_sh, lrun_sh, alpha_sh;

    const int tid  = threadIdx.x;
    const int w    = tid >> 6;        // wave 0..7 -> n slice [64w, 64w+64)
    const int lane = tid & 63;
    const int ml   = lane & 15;
    const int quad = lane >> 4;
    const int bid  = blockIdx.x;
    const int b    = bid >> 5;        // 32 blocks per batch row
    const int g    = bid & 31;
    const int s0   = g << 8;          // 256 rows per block

    // staging map: thread t covers row m = t>>4, k = (t&15)*4 + 64h, h=0..7
    const int m   = tid >> 4;
    const int q16 = tid & 15;
    const int stb = ((m >> 4) * 512) + (((m & 15) + 16 * ((q16 >> 1) & 3)) * 8) + (q16 & 1) * 4;
    const int jt  = q16 >> 3;         // j = 2h + jt
    const float* kr = keys + ((size_t)(b * SS + s0 + m)) * DD + q16 * 4;

    // prologue: init running state, preload mask, stage chunk 0 -> buf 0
    c_run[tid] = 0.0f;
    if (tid < 256) mask_sh[tid] = mask[b * SS + s0 + tid];
    if (tid == 0) { mrun_sh = NEG_HUGE; lrun_sh = 0.0f; }

    const unsigned short* wfb = WkT_f + (size_t)w * 32768 + lane * 8;
    float qv[4], vv[4];
#pragma unroll
    for (int jn = 0; jn < 4; ++jn) {
        const int n = w * 64 + jn * 16 + ml;
        qv[jn] = qproj[b * DD + n];
        vv[jn] = vvec[n];
    }
    {
        f32x4 pf[8];
#pragma unroll
        for (int h = 0; h < 8; ++h) pf[h] = *(const f32x4*)(kr + h * 64);
#pragma unroll
        for (int h = 0; h < 8; ++h) cvt_store_bf4(&ksA[0][(2 * h + jt) * 1024 + stb], pf[h]);
    }
    __syncthreads();

    for (int i = 0; i < 8; ++i) {
        const int cur = i & 1, nxt = cur ^ 1;

        // issue next chunk's loads; sched_barrier pins them above the K-loop
        f32x4 pf[8];
        if (i < 7) {
            const float* kp = kr + (size_t)(i + 1) * 32 * DD;
#pragma unroll
            for (int h = 0; h < 8; ++h) pf[h] = *(const f32x4*)(kp + h * 64);
        }
        __builtin_amdgcn_sched_barrier(0);

        // --- K loop: A from LDS buf cur, B from L2 ---
        f32x4 acc[2][4];
#pragma unroll
        for (int it = 0; it < 2; ++it)
#pragma unroll
            for (int jn = 0; jn < 4; ++jn) acc[it][jn] = (f32x4){0.f, 0.f, 0.f, 0.f};

#pragma unroll 4
        for (int j = 0; j < 16; ++j) {
            bf16x8 af0 = *(const bf16x8*)&ksA[cur][j * 1024 + lane * 8];
            bf16x8 af1 = *(const bf16x8*)&ksA[cur][j * 1024 + 512 + lane * 8];
#pragma unroll
            for (int jn = 0; jn < 4; ++jn) {
                bf16x8 bfr = *(const bf16x8*)(wfb + ((jn * 16 + j) << 9));
                acc[0][jn] = __builtin_amdgcn_mfma_f32_16x16x32_bf16(af0, bfr, acc[0][jn], 0, 0, 0);
                acc[1][jn] = __builtin_amdgcn_mfma_f32_16x16x32_bf16(af1, bfr, acc[1][jn], 0, 0, 0);
            }
        }

        // store prefetched chunk into idle buffer (loads landed during K-loop)
        if (i < 7) {
#pragma unroll
            for (int h = 0; h < 8; ++h)
                cvt_store_bf4(&ksA[nxt][(2 * h + jt) * 1024 + stb], pf[h]);
        }

        // --- epilogue: e-partials. C layout: row = it*16 + quad*4 + r, col = ml
#pragma unroll
        for (int it = 0; it < 2; ++it) {
#pragma unroll
            for (int r = 0; r < 4; ++r) {
                float s = 0.0f;
#pragma unroll
                for (int jn = 0; jn < 4; ++jn) {
                    float x  = acc[it][jn][r] + qv[jn];
                    float e2 = __expf(2.0f * x);
                    float rc = __builtin_amdgcn_rcpf(e2 + 1.0f);
                    s += vv[jn] - 2.0f * vv[jn] * rc;    // tanh(x)*v
                }
                s += __shfl_xor(s, 1, 64);
                s += __shfl_xor(s, 2, 64);
                s += __shfl_xor(s, 4, 64);
                s += __shfl_xor(s, 8, 64);
                if (ml == 0) sm_part[w][it * 16 + quad * 4 + r] = s;
            }
        }
        __syncthreads();

        // --- stats (32 threads), block-level online softmax ---
        if (tid < 32) {
            float e = 0.0f;
#pragma unroll
            for (int w8 = 0; w8 < 8; ++w8) e += sm_part[w8][tid];
            const int mk = mask_sh[i * 32 + tid];
            if (mk == 0) e = NEG_HUGE;
            e_ws[(size_t)b * SS + s0 + i * 32 + tid] = e;
            float mx = e;
#pragma unroll
            for (int off = 16; off >= 1; off >>= 1) mx = fmaxf(mx, __shfl_xor(mx, off, 64));
            float wv = (mk == 0) ? 0.0f : __expf(e - mx);
            float lc = wv;
#pragma unroll
            for (int off = 16; off >= 1; off >>= 1) lc += __shfl_xor(lc, off, 64);
            const float m_old = mrun_sh;
            const float m_new = fmaxf(m_old, mx);
            const float alpha = __expf(m_old - m_new);   // 0 on first chunk
            const float beta  = __expf(mx - m_new);
            w_sh[tid] = wv * beta;
            if (tid == 0) {
                mrun_sh  = m_new;
                lrun_sh  = lrun_sh * alpha + lc * beta;
                alpha_sh = alpha;
            }
        }
        __syncthreads();

        // --- context: column-per-thread, keys L2-hot, online rescale ---
        {
            const float alpha = alpha_sh;
            float cacc = c_run[tid] * alpha;
            const float* kcol = keys + ((size_t)(b * SS + s0 + i * 32)) * DD + tid;
#pragma unroll
            for (int sI = 0; sI < 32; sI += 8) {
                float kvv[8];
#pragma unroll
                for (int u = 0; u < 8; ++u) kvv[u] = kcol[(size_t)(sI + u) * DD];
#pragma unroll
                for (int u = 0; u < 8; ++u) cacc = fmaf(w_sh[sI + u], kvv[u], cacc);
            }
            c_run[tid] = cacc;
        }
    }

    __syncthreads();
    cpart[(size_t)bid * 512 + tid] = c_run[tid];
    if (tid == 0) ml_ws[bid] = make_float2(mrun_sh, lrun_sh);
}

// ---------------------------------------------------------------------------
// Kernel 3: finalize over 32 partials per batch row.
//  blocks 0..15:    c[b][n] = (sum_g cpart[b][g][n]*exp(m_g-M)) / L
//  blocks 16..143:  a[b][s] = exp(e[b][s]-M)/L   (1024 s per block)
// ---------------------------------------------------------------------------
__global__ __launch_bounds__(256) void finalize_kernel(
    const float* __restrict__ e_ws, const float* __restrict__ cpart,
    const float2* __restrict__ ml_ws, float* __restrict__ out)
{
    const int bid = blockIdx.x, t = threadIdx.x;
    const int b = (bid < 16) ? bid : ((bid - 16) >> 3);

    float M = NEG_HUGE;
#pragma unroll
    for (int g2 = 0; g2 < 32; ++g2) M = fmaxf(M, ml_ws[b * 32 + g2].x);
    float L = 0.0f;
#pragma unroll
    for (int g2 = 0; g2 < 32; ++g2) {
        float2 p = ml_ws[b * 32 + g2];
        L += p.y * __expf(p.x - M);
    }
    const float invL = 1.0f / L;

    if (bid < 16) {
        const int n0 = t * 2;
        float a0 = 0.0f, a1 = 0.0f;
#pragma unroll 4
        for (int g2 = 0; g2 < 32; ++g2) {
            const float sc = __expf(ml_ws[b * 32 + g2].x - M);
            const float* cp = cpart + ((size_t)(b * 32 + g2)) * 512 + n0;
            a0 = fmaf(cp[0], sc, a0);
            a1 = fmaf(cp[1], sc, a1);
        }
        out[b * DD + n0]     = a0 * invL;
        out[b * DD + n0 + 1] = a1 * invL;
    } else {
        const int chunk8 = (bid - 16) & 7;
        const float* ep = e_ws + (size_t)b * SS + chunk8 * 1024;
        float* ap = out + BB * DD + (size_t)b * SS + chunk8 * 1024;
#pragma unroll
        for (int r = 0; r < 4; ++r) {
            float e = ep[t + 256 * r];
            ap[t + 256 * r] = __expf(e - M) * invL;
        }
    }
}

// ---------------------------------------------------------------------------
extern "C" void kernel_launch(void* const* d_in, const int* in_sizes, int n_in,
                              void* d_out, int out_size, void* d_ws, size_t ws_size,
                              hipStream_t stream)
{
    const float* query = (const float*)d_in[0];
    const float* keys  = (const float*)d_in[1];
    const int*   mask  = (const int*)  d_in[2];
    const float* Wq    = (const float*)d_in[3];
    const float* Wk    = (const float*)d_in[4];
    const float* v     = (const float*)d_in[5];
    float* out = (float*)d_out;

    // workspace layout
    float*          qproj = (float*)d_ws;                                   // 32 KB
    unsigned short* WkT_f = (unsigned short*)((char*)d_ws + 32768);         // 512 KB
    float*          e_ws  = (float*)((char*)d_ws + 32768 + 524288);         // 512 KB
    float*          cpart = (float*)((char*)d_ws + 32768 + 2 * 524288);     // 1 MB
    float2*         ml_ws = (float2*)((char*)d_ws + 32768 + 2 * 524288 + 1048576); // 4 KB

    prep_kernel    <<<96, 256, 0, stream>>>(query, Wq, Wk, qproj, WkT_f);
    fused_kernel   <<<512, 512, 0, stream>>>(keys, WkT_f, qproj, v, mask,
                                             e_ws, cpart, ml_ws);
    finalize_kernel<<<16 + 128, 256, 0, stream>>>(e_ws, cpart, ml_ws, out);
}